// Round 3
// baseline (833.169 us; speedup 1.0000x reference)
//
#include <hip/hip_runtime.h>
#include <stdint.h>

// Problem constants (from reference setup_inputs) — ALL TENSORS ARE FLOAT32.
#define T_STEPS 100
#define BATCH   65536
#define NI      2
#define NH      10
#define NO      4

// Native clang vector types (legal operands for __builtin_nontemporal_*).
typedef float vf2 __attribute__((ext_vector_type(2)));
typedef float vf4 __attribute__((ext_vector_type(4)));

// One thread per batch element; whole T=100 scan in registers.
// Memory-bound: 734 MB fp32 writes + 52 MB reads => ~130 us roofline.
__global__ __launch_bounds__(256, 1) void snn_fwd(
    const float* __restrict__ x,    // (T, B, NI)
    const float* __restrict__ W1,   // (NH, NI)
    const float* __restrict__ b1,   // (NH)
    const float* __restrict__ W2,   // (NO, NH)
    const float* __restrict__ b2,   // (NO)
    float* __restrict__ out)        // spk1 | mem1 | spk2 | mem2, concat flat
{
    const int b = blockIdx.x * blockDim.x + threadIdx.x;

    // Weights: wave-uniform addresses -> scalar (s_load) cached reads.
    float w1[NH][NI], bb1[NH], w2[NO][NH], bb2[NO];
#pragma unroll
    for (int h = 0; h < NH; ++h) {
        w1[h][0] = W1[h * NI + 0];
        w1[h][1] = W1[h * NI + 1];
        bb1[h]   = b1[h];
    }
#pragma unroll
    for (int o = 0; o < NO; ++o) {
#pragma unroll
        for (int h = 0; h < NH; ++h) w2[o][h] = W2[o * NH + h];
        bb2[o] = b2[o];
    }

    float m1[NH], m2[NO];
#pragma unroll
    for (int h = 0; h < NH; ++h) m1[h] = 0.0f;
#pragma unroll
    for (int o = 0; o < NO; ++o) m2[o] = 0.0f;

    // Output section pointers (layout matches reference return order).
    const size_t sec = (size_t)T_STEPS * BATCH;
    float* o_spk1 = out + (size_t)b * NH;                        // (T,B,NH)
    float* o_mem1 = out + sec * NH + (size_t)b * NH;             // (T,B,NH)
    float* o_spk2 = out + 2 * sec * NH + (size_t)b * NO;         // (T,B,NO)
    float* o_mem2 = out + 2 * sec * NH + sec * NO + (size_t)b * NO;

    // x as vf2 (8B per thread per step), coalesced; prefetch depth 2 to cover
    // ~900cy HBM latency at 1 wave/SIMD occupancy.
    const vf2* xp = (const vf2*)x + b;
    vf2 xc = __builtin_nontemporal_load(xp);
    vf2 xn = __builtin_nontemporal_load(xp + BATCH);

    for (int t = 0; t < T_STEPS; ++t) {
        vf2 xf;
        xf.x = 0.0f; xf.y = 0.0f;
        if (t + 2 < T_STEPS) xf = __builtin_nontemporal_load(xp + 2 * BATCH);
        xp += BATCH;

        const float x0 = xc.x;
        const float x1 = xc.y;

        // Layer 1 LIF. fmaf(x1,w1, x0*w0) = BLAS ascending-k FMA order.
        // 0.5*m is exact, reset*THR is exact => recurrence reproducible.
        float spk1[NH];
#pragma unroll
        for (int h = 0; h < NH; ++h) {
            float syn   = __builtin_fmaf(x1, w1[h][1], x0 * w1[h][0]) + bb1[h];
            float reset = (m1[h] > 1.0f) ? 1.0f : 0.0f;   // pre-update membrane, detached
            float m     = 0.5f * m1[h] + syn;
            m           = m - reset;
            m1[h]       = m;
            spk1[h]     = ((m - 1.0f) > 0.0f) ? 1.0f : 0.0f;
        }

        // Layer 2 LIF. spk in {0,1} => products exact; ascending-h sequential sum
        // matches BLAS; bias added last (separate add, as in reference).
        float spk2[NO];
#pragma unroll
        for (int o = 0; o < NO; ++o) {
            float acc = spk1[0] * w2[o][0];
#pragma unroll
            for (int h = 1; h < NH; ++h) acc = __builtin_fmaf(spk1[h], w2[o][h], acc);
            float syn   = acc + bb2[o];
            float reset = (m2[o] > 1.0f) ? 1.0f : 0.0f;
            float m     = 0.5f * m2[o] + syn;
            m           = m - reset;
            m2[o]       = m;
            spk2[o]     = ((m - 1.0f) > 0.0f) ? 1.0f : 0.0f;
        }

        // Stores: plain (temporal) — L2 aggregates the 8B-strided writes into
        // full lines before HBM writeback (nt stores would risk partial bursts).
        // NH arrays: 40B/thread, 8B-aligned -> 5x dwordx2 each.
        {
            vf2* ps = (vf2*)o_spk1;
            vf2* pm = (vf2*)o_mem1;
#pragma unroll
            for (int i = 0; i < 5; ++i) {
                vf2 vs; vs.x = spk1[2 * i]; vs.y = spk1[2 * i + 1];
                vf2 vm; vm.x = m1[2 * i];   vm.y = m1[2 * i + 1];
                ps[i] = vs;
                pm[i] = vm;
            }
        }
        // NO arrays: 16B/thread, 16B-aligned -> one dwordx4 each.
        {
            vf4 vs; vs.x = spk2[0]; vs.y = spk2[1]; vs.z = spk2[2]; vs.w = spk2[3];
            vf4 vm; vm.x = m2[0];   vm.y = m2[1];   vm.z = m2[2];   vm.w = m2[3];
            *(vf4*)o_spk2 = vs;
            *(vf4*)o_mem2 = vm;
        }

        o_spk1 += (size_t)BATCH * NH;
        o_mem1 += (size_t)BATCH * NH;
        o_spk2 += (size_t)BATCH * NO;
        o_mem2 += (size_t)BATCH * NO;
        xc = xn;
        xn = xf;
    }
}

extern "C" void kernel_launch(void* const* d_in, const int* in_sizes, int n_in,
                              void* d_out, int out_size, void* d_ws, size_t ws_size,
                              hipStream_t stream) {
    const float* x  = (const float*)d_in[0];
    const float* W1 = (const float*)d_in[1];
    const float* b1 = (const float*)d_in[2];
    const float* W2 = (const float*)d_in[3];
    const float* b2 = (const float*)d_in[4];
    float* out = (float*)d_out;

    snn_fwd<<<BATCH / 256, 256, 0, stream>>>(x, W1, b1, W2, b2, out);
}